// Round 8
// baseline (394.653 us; speedup 1.0000x reference)
//
#include <hip/hip_runtime.h>
#include <math.h>

#define NCLS 19
#define HW   (512*1024)          // 524288
#define CHW  (NCLS*HW)
#define TPIX (2*HW)              // 1048576
#define NB   512                 // coarse bins
#define NPART 32                 // partial histogram copies (u16, 622KB cap)
#define CAND_MAX 4096
#define SUBB 1024                // refinement sub-bins per coarse bin
#define SCAP 256                 // refinement candidate cap (per class)
#define GRID_CO 256              // fused-tail blocks: 1/CU -> 2x co-residency margin

// ---- workspace layout (bytes) ----
#define WS_PART   0                          // 32*19*512*2 = 622592
#define WS_CANDC  622592                     // NCLS*4 candidate counters
#define WS_ACCUM  622720                     // [0]=sum_loss f32, [1]=cnt_mask u32, [2]=cnt_solid u32
#define WS_BAR    622784                     // 8 barrier counters (u32)
#define WS_SEL    622848                     // NCLS * {int bin, int rank}
#define WS_NEWTH  623360                     // NCLS*4
#define WS_CONF   623616                     // TPIX*4
#define WS_LOSS   4817920                    // TPIX*4
#define WS_LABEL  9012224                    // TPIX*1
#define WS_CAND   10060800                   // NCLS*CAND_MAX*4 -> end 10372096

// ---------------- K1: register-path staging (unchanged R7; empirical floor 62us) ----------------
// Four disjoint staging structures (R1/R3/R6/R7) all pin at 62us: the 2MB-stride
// 38-plane gather pattern itself runs at ~2.6 TB/s on this chip. Leave it.
#define CH_STRIDE4 (HW/4)                    // channel stride in float4 units
__global__ __launch_bounds__(256, 4)
void k1_pixel(const float* __restrict__ lb_t, const float* __restrict__ la_t,
              float* __restrict__ conf_o, float* __restrict__ loss_o,
              unsigned char* __restrict__ label_o,
              unsigned int* __restrict__ cand_cnt,
              unsigned int* __restrict__ accum_u,
              unsigned int* __restrict__ bar)
{
    const int tid = threadIdx.x;
    if (blockIdx.x == 0) {                   // zero control words for the fused tail
        if (tid < NCLS)             cand_cnt[tid] = 0u;
        else if (tid < NCLS + 3)    accum_u[tid - NCLS] = 0u;
        else if (tid < NCLS + 11)   bar[tid - NCLS - 3] = 0u;
    }
    const int g    = blockIdx.x * 256 + tid; // float4 index
    const int pix0 = g << 2;
    const int n    = pix0 >> 19;
    const int rem  = pix0 & (HW - 1);
    const float4* bb = (const float4*)(lb_t + (size_t)n * CHW + rem);
    const float4* ab = (const float4*)(la_t + (size_t)n * CHW + rem);

    float mb[4], zb[4], dot[4], ma[4], za[4], a_lab[4];
    int lab[4];
#pragma unroll
    for (int j = 0; j < 4; ++j) {
        mb[j] = -INFINITY; ma[j] = -INFINITY;
        zb[j] = 0.0f; za[j] = 0.0f; dot[j] = 0.0f; a_lab[j] = 0.0f; lab[j] = -1;
    }

    float4 bA0, bA1, bA2, bA3, aA0, aA1, aA2, aA3;     // buffer A
    float4 bB0, bB1, bB2, bB3, aB0, aB1, aB2, aB3;     // buffer B

#define LOADA(c0, NC)                                                          \
    do {                                                                       \
        bA0 = bb[(size_t)(c0 + 0) * CH_STRIDE4];                               \
        aA0 = ab[(size_t)(c0 + 0) * CH_STRIDE4];                               \
        if (NC > 1) { bA1 = bb[(size_t)(c0 + 1) * CH_STRIDE4];                 \
                      aA1 = ab[(size_t)(c0 + 1) * CH_STRIDE4]; }               \
        if (NC > 2) { bA2 = bb[(size_t)(c0 + 2) * CH_STRIDE4];                 \
                      aA2 = ab[(size_t)(c0 + 2) * CH_STRIDE4]; }               \
        if (NC > 3) { bA3 = bb[(size_t)(c0 + 3) * CH_STRIDE4];                 \
                      aA3 = ab[(size_t)(c0 + 3) * CH_STRIDE4]; }               \
        __builtin_amdgcn_sched_barrier(0);                                     \
    } while (0)
#define LOADB(c0, NC)                                                          \
    do {                                                                       \
        bB0 = bb[(size_t)(c0 + 0) * CH_STRIDE4];                               \
        aB0 = ab[(size_t)(c0 + 0) * CH_STRIDE4];                               \
        if (NC > 1) { bB1 = bb[(size_t)(c0 + 1) * CH_STRIDE4];                 \
                      aB1 = ab[(size_t)(c0 + 1) * CH_STRIDE4]; }               \
        if (NC > 2) { bB2 = bb[(size_t)(c0 + 2) * CH_STRIDE4];                 \
                      aB2 = ab[(size_t)(c0 + 2) * CH_STRIDE4]; }               \
        if (NC > 3) { bB3 = bb[(size_t)(c0 + 3) * CH_STRIDE4];                 \
                      aB3 = ab[(size_t)(c0 + 3) * CH_STRIDE4]; }               \
        __builtin_amdgcn_sched_barrier(0);                                     \
    } while (0)
#define STEP(c, bv, av)                                                        \
    do {                                                                       \
        _Pragma("unroll")                                                      \
        for (int j = 0; j < 4; ++j) {                                          \
            float b = ((const float*)&(bv))[j];                                \
            float a = ((const float*)&(av))[j];                                \
            float mn = fmaxf(mb[j], b);                                        \
            float eo = __expf(mb[j] - mn);     /* exp(-inf)=0 handles init */  \
            float en = __expf(b - mn);                                         \
            zb[j]  = zb[j] * eo + en;                                          \
            dot[j] = dot[j] * eo + en * a;                                     \
            bool upd = b > mb[j];              /* first-max-wins (strict >) */ \
            lab[j]   = upd ? (c) : lab[j];                                     \
            a_lab[j] = upd ? a : a_lab[j];                                     \
            mb[j] = mn;                                                        \
            float mna = fmaxf(ma[j], a);                                       \
            za[j] = za[j] * __expf(ma[j] - mna) + __expf(a - mna);             \
            ma[j] = mna;                                                       \
        }                                                                      \
    } while (0)

    LOADA(0, 4);
    LOADB(4, 4);
    STEP(0, bA0, aA0); STEP(1, bA1, aA1); STEP(2, bA2, aA2); STEP(3, bA3, aA3);
    LOADA(8, 4);
    STEP(4, bB0, aB0); STEP(5, bB1, aB1); STEP(6, bB2, aB2); STEP(7, bB3, aB3);
    LOADB(12, 4);
    STEP(8, bA0, aA0); STEP(9, bA1, aA1); STEP(10, bA2, aA2); STEP(11, bA3, aA3);
    LOADA(16, 3);
    STEP(12, bB0, aB0); STEP(13, bB1, aB1); STEP(14, bB2, aB2); STEP(15, bB3, aB3);
    STEP(16, bA0, aA0); STEP(17, bA1, aA1); STEP(18, bA2, aA2);

    float4 cf4, ls4; uchar4 lb4;
#pragma unroll
    for (int j = 0; j < 4; ++j) {
        float cf = 1.0f / zb[j];
        float pa_lab = __expf(a_lab[j] - ma[j]) / za[j];
        float ls = (1.0f - pa_lab) * (ma[j] + __logf(za[j]) - dot[j] / zb[j]);
        ((float*)&cf4)[j] = cf;
        ((float*)&ls4)[j] = ls;
        ((unsigned char*)&lb4)[j] = (unsigned char)lab[j];
    }
    ((float4*)conf_o)[g] = cf4;
    ((float4*)loss_o)[g] = ls4;
    ((uchar4*)label_o)[g] = lb4;
#undef LOADA
#undef LOADB
#undef STEP
}

// ---- hand-rolled grid barrier: bounded spin -> co-residency failure becomes a
// finite wrong-answer run, never a hang. Fence mechanics = R3/R5-proven ticket
// pattern + spin. 256 blocks at 1/CU (launch_bounds caps 2 blk/CU) -> 2x margin.
__device__ __forceinline__ void grid_barrier(unsigned int* cnt, unsigned nb)
{
    __threadfence();                          // release (every thread)
    __syncthreads();
    if (threadIdx.x == 0) {
        atomicAdd(cnt, 1u);
        int it = 0;
        while (atomicAdd(cnt, 0u) < nb && it < (1 << 20)) {   // ~0.2s cap
            __builtin_amdgcn_s_sleep(8);
            ++it;
        }
    }
    __syncthreads();
    __threadfence();                          // acquire (every thread)
}

// ---------------- K2: fused tail, normal launch, manual grid barriers ----------------
// P0 hist(32 blks) | P1 select(19) | P2 gather(all) | P3 thresh(19) | P4 reduce+out
// All phase bodies are byte-identical to the R3/R7-proven standalone kernels.
__global__ __launch_bounds__(256, 2)
void k2_fused(const float4* __restrict__ conf4, const float4* __restrict__ loss4,
              const uchar4* __restrict__ label4,
              unsigned short* __restrict__ part, const float* __restrict__ cls_thresh,
              int* __restrict__ sel, unsigned int* __restrict__ cand_cnt,
              float* __restrict__ cand, float* __restrict__ newth,
              float* __restrict__ accum, unsigned int* __restrict__ bar,
              float* __restrict__ out)
{
    __shared__ unsigned int shm[NCLS * NB];            // 38912 B, re-purposed per phase
    const int t = threadIdx.x;
    const int b = blockIdx.x;
    const unsigned nb = gridDim.x;

    // ======== P0: blocks 0..31 build u16 partial histograms ========
    if (b < NPART) {
        for (int w = t; w < NCLS * NB; w += 256) shm[w] = 0u;
        __syncthreads();
        const int per4  = TPIX / 4 / NPART;            // 8192 float4 per block
        const int base4 = b * per4;
        for (int i = 0; i < per4 / 256; ++i) {         // 32 iterations
            int g = base4 + i * 256 + t;
            float4 c4 = conf4[g];
            uchar4 l4 = label4[g];
            float cf[4] = {c4.x, c4.y, c4.z, c4.w};
            int   lb[4] = {l4.x, l4.y, l4.z, l4.w};
#pragma unroll
            for (int k = 0; k < 4; ++k) {
                int bin = (int)(cf[k] * (float)NB);
                bin = bin < (NB - 1) ? bin : (NB - 1);
                atomicAdd(&shm[lb[k] * NB + bin], 1u); // LDS atomic only
            }
        }
        __syncthreads();
        unsigned short* dst = part + b * (NCLS * NB);
        for (int w = t; w < NCLS * NB; w += 256) dst[w] = (unsigned short)shm[w];
    }
    grid_barrier(&bar[0], nb);

    // ======== P1: blocks 0..18 rank-select (bin, rank-in-bin) ========
    if (b < NCLS) {
        const int c = b;
        unsigned* sc = shm;                            // [256]
        float thr = cls_thresh[c];
        int thr_bin = (int)(thr * (float)NB); thr_bin = thr_bin < (NB-1) ? thr_bin : (NB-1);
        int base = NB - (t + 1) * 2;                   // descending 2-bin chunk
        unsigned h0 = 0, h1 = 0;
#pragma unroll 8
        for (int p = 0; p < NPART; ++p) {
            const unsigned short* pp = part + p * (NCLS * NB) + c * NB;
            h0 += pp[base];
            h1 += pp[base + 1];
        }
        if (base == thr_bin)     h0 += 1u;             // extended multiset: append thr
        if (base + 1 == thr_bin) h1 += 1u;
        unsigned s = h0 + h1;
        sc[t] = s;
        __syncthreads();
        for (int off = 1; off < 256; off <<= 1) {
            unsigned vt = sc[t];
            unsigned vp = (t >= off) ? sc[t - off] : 0u;
            __syncthreads();
            sc[t] = vt + vp;
            __syncthreads();
        }
        unsigned total_ext = sc[255];                  // count_c + 1
        unsigned cnt = total_ext - 1u;
        int idx = (int)floorf((float)(cnt + 1u) * 0.2f * powf(thr, 8.0f));
        unsigned above = sc[t] - s;
        if ((unsigned)idx >= above && (unsigned)idx < above + s) {
            int B, r;
            if ((unsigned)idx < above + h1) { B = base + 1; r = (int)((unsigned)idx - above); }
            else                            { B = base;     r = (int)((unsigned)idx - above - h1); }
            sel[2 * c]     = B;
            sel[2 * c + 1] = r;
            if (B == thr_bin) {                        // appended thr is a candidate
                unsigned pos = atomicAdd(&cand_cnt[c], 1u);
                if (pos < CAND_MAX) cand[c * CAND_MAX + pos] = thr;
            }
        }
    }
    grid_barrier(&bar[1], nb);

    // ======== P2: all blocks gather selection-bin candidates (grid-stride) ========
    for (int g = b * 256 + t; g < TPIX / 4; g += GRID_CO * 256) {
        float4 c4 = conf4[g];
        uchar4 l4 = label4[g];
        float cf[4] = {c4.x, c4.y, c4.z, c4.w};
        int   lb[4] = {l4.x, l4.y, l4.z, l4.w};
#pragma unroll
        for (int i = 0; i < 4; ++i) {
            int bin = (int)(cf[i] * (float)NB);
            bin = bin < (NB - 1) ? bin : (NB - 1);
            if (bin == sel[2 * lb[i]]) {
                unsigned pos = atomicAdd(&cand_cnt[lb[i]], 1u);
                if (pos < CAND_MAX) cand[lb[i] * CAND_MAX + pos] = cf[i];
            }
        }
    }
    grid_barrier(&bar[2], nb);

    // ======== P3: blocks 0..18 sub-bin refined exact rank -> newth ========
    if (b < NCLS) {
        const int c = b;
        unsigned int* subh = shm;                      // [SUBB]
        unsigned int* scnt = shm + SUBB;
        int*          sS   = (int*)(shm + SUBB + 1);
        unsigned int* sR2  = shm + SUBB + 2;
        float*        sres = (float*)(shm + SUBB + 3);
        float*        sbuf = (float*)(shm + SUBB + 4); // [SCAP]

        unsigned mc = cand_cnt[c];
        int m = (int)(mc < (unsigned)CAND_MAX ? mc : (unsigned)CAND_MAX);
        int B = sel[2 * c];
        int r = sel[2 * c + 1];
        const float* v = cand + c * CAND_MAX;
        const float scale = (float)NB;

        for (int i = t; i < SUBB; i += 256) subh[i] = 0u;
        if (t == 0) { *scnt = 0u; *sS = 0; *sR2 = 0u; *sres = 0.0f; }
        __syncthreads();

        for (int i = t; i < m; i += 256) {
            float x = v[i];
            int s = (int)((x * scale - (float)B) * (float)SUBB);
            s = s < 0 ? 0 : (s > SUBB - 1 ? SUBB - 1 : s);
            atomicAdd(&subh[s], 1u);
        }
        __syncthreads();

        if (t < 64) {                                  // wave 0: descending scan
            int lane = t;
            int cb = SUBB - 16 * (lane + 1);
            unsigned hsum = 0;
            for (int i = 0; i < 16; ++i) hsum += subh[cb + i];
            unsigned incl = hsum;
            for (int off = 1; off < 64; off <<= 1) {
                unsigned q = __shfl_up(incl, off, 64);
                if (lane >= off) incl += q;
            }
            unsigned above = incl - hsum;
            if ((unsigned)r >= above && (unsigned)r < above + hsum) {
                unsigned cum = above;
                for (int i = 15; i >= 0; --i) {
                    unsigned h = subh[cb + i];
                    if ((unsigned)r < cum + h) { *sS = cb + i; *sR2 = (unsigned)r - cum; break; }
                    cum += h;
                }
            }
        }
        __syncthreads();
        const int S = *sS;
        const unsigned r2 = *sR2;

        for (int i = t; i < m; i += 256) {             // gather sub-bin members
            float x = v[i];
            int s = (int)((x * scale - (float)B) * (float)SUBB);
            s = s < 0 ? 0 : (s > SUBB - 1 ? SUBB - 1 : s);
            if (s == S) {
                unsigned p = atomicAdd(scnt, 1u);
                if (p < (unsigned)SCAP) sbuf[p] = x;
            }
        }
        __syncthreads();
        unsigned cntS = *scnt;

        if (cntS <= (unsigned)SCAP) {
            for (int i = t; i < (int)cntS; i += 256) {
                float x = sbuf[i];
                int gc = 0, e = 0;
                for (int j = 0; j < (int)cntS; ++j) {
                    float y = sbuf[j];
                    gc += (y > x); e += (y == x);
                }
                if (gc <= (int)r2 && (int)r2 < gc + e) *sres = x;
            }
        } else {
            // safety fallback (dead in practice): exact rank restricted to sub-bin S
            for (int i = t; i < m; i += 256) {
                float x = v[i];
                int s = (int)((x * scale - (float)B) * (float)SUBB);
                s = s < 0 ? 0 : (s > SUBB - 1 ? SUBB - 1 : s);
                if (s != S) continue;
                int gc = 0, e = 0;
                for (int j = 0; j < m; ++j) {
                    float y = v[j];
                    int sj = (int)((y * scale - (float)B) * (float)SUBB);
                    sj = sj < 0 ? 0 : (sj > SUBB - 1 ? SUBB - 1 : sj);
                    if (sj != S) continue;
                    gc += (y > x); e += (y == x);
                }
                if (gc <= (int)r2 && (int)r2 < gc + e) *sres = x;
            }
        }
        __syncthreads();
        if (t == 0) {
            float thr = cls_thresh[c];
            float nt = 0.9f * thr + 0.1f * (*sres);
            if (nt >= 1.0f) nt = 0.999f;
            newth[c] = nt;
        }
    }
    grid_barrier(&bar[3], nb);

    // ======== P4: all blocks masked reduction (grid-stride) ========
    {
        float* th   = (float*)shm;                     // [NCLS]
        float* s_ls = (float*)(shm + 32);              // [4]
        int*   s_m  = (int*)(shm + 36);
        int*   s_s  = (int*)(shm + 40);
        if (t < NCLS) th[t] = newth[t];
        __syncthreads();

        float ls = 0.0f; int mask = 0, solid = 0;
        for (int g = b * 256 + t; g < TPIX / 4; g += GRID_CO * 256) {
            float4 c4 = conf4[g];
            float4 s4 = loss4[g];
            uchar4 l4 = label4[g];
            float cf[4] = {c4.x, c4.y, c4.z, c4.w};
            float lv[4] = {s4.x, s4.y, s4.z, s4.w};
            int   lb[4] = {l4.x, l4.y, l4.z, l4.w};
#pragma unroll
            for (int i = 0; i < 4; ++i) {
                bool m = cf[i] > th[lb[i]];
                mask  += m ? 1 : 0;
                solid += (cf[i] > 0.8f) ? 1 : 0;
                ls    += m ? fmaxf(lv[i], 1e-8f) : 0.0f;
            }
        }
        for (int off = 32; off > 0; off >>= 1) {
            ls    += __shfl_down(ls, off, 64);
            mask  += __shfl_down(mask, off, 64);
            solid += __shfl_down(solid, off, 64);
        }
        int w = t >> 6;
        if ((t & 63) == 0) { s_ls[w] = ls; s_m[w] = mask; s_s[w] = solid; }
        __syncthreads();
        if (t == 0) {
            float L = s_ls[0] + s_ls[1] + s_ls[2] + s_ls[3];
            int   M = s_m[0] + s_m[1] + s_m[2] + s_m[3];
            int   S = s_s[0] + s_s[1] + s_s[2] + s_s[3];
            atomicAdd(&accum[0], L);
            atomicAdd(&((unsigned int*)accum)[1], (unsigned)M);
            atomicAdd(&((unsigned int*)accum)[2], (unsigned)S);
        }
    }
    grid_barrier(&bar[4], nb);

    // ======== out (block 0; atomic reads = coherent-point reads) ========
    if (b == 0 && t == 0) {
        float sum   = atomicAdd(&accum[0], 0.0f);
        unsigned cm = atomicAdd(&((unsigned int*)accum)[1], 0u);
        unsigned cs = atomicAdd(&((unsigned int*)accum)[2], 0u);
        out[0] = sum / fmaxf((float)cm, 1.0f);
        out[1] = (float)cm / (float)TPIX;
        out[2] = (float)cs / (float)TPIX;
    }
}

extern "C" void kernel_launch(void* const* d_in, const int* in_sizes, int n_in,
                              void* d_out, int out_size, void* d_ws, size_t ws_size,
                              hipStream_t stream)
{
    const float* lb  = (const float*)d_in[0];
    const float* la  = (const float*)d_in[1];
    const float* cth = (const float*)d_in[2];
    float* out = (float*)d_out;

    char* ws = (char*)d_ws;
    unsigned short* part     = (unsigned short*)(ws + WS_PART);
    unsigned int*   cand_cnt = (unsigned int*)(ws + WS_CANDC);
    float*          accum    = (float*)(ws + WS_ACCUM);
    unsigned int*   bar      = (unsigned int*)(ws + WS_BAR);
    int*            sel      = (int*)(ws + WS_SEL);
    float*          newth    = (float*)(ws + WS_NEWTH);
    float*          conf     = (float*)(ws + WS_CONF);
    float*          loss     = (float*)(ws + WS_LOSS);
    unsigned char*  label    = (unsigned char*)(ws + WS_LABEL);
    float*          cand     = (float*)(ws + WS_CAND);

    dim3 grd1(TPIX / 4 / 256);           // 1024 blocks, 4 px/thread, register path

    k1_pixel<<<grd1, dim3(256), 0, stream>>>(lb, la, conf, loss, label,
                                             cand_cnt, (unsigned int*)accum, bar);
    k2_fused<<<dim3(GRID_CO), dim3(256), 0, stream>>>(
        (const float4*)conf, (const float4*)loss, (const uchar4*)label,
        part, cth, sel, cand_cnt, cand, newth, accum, bar, out);
}

// Round 9
// 247.403 us; speedup vs baseline: 1.5952x; 1.5952x over previous
//
#include <hip/hip_runtime.h>
#include <math.h>

#define NCLS 19
#define HW   (512*1024)          // 524288
#define CHW  (NCLS*HW)
#define TPIX (2*HW)              // 1048576
#define NB   512                 // coarse bins
#define NPART 32                 // partial histogram copies (u16, fills 622KB slot)
#define CAND_MAX 4096
#define SUBB 1024                // refinement sub-bins per coarse bin
#define SCAP 256                 // refinement candidate cap (per class)

// ---- workspace layout (bytes) ----
#define WS_PART   0                          // 32*19*512*2 = 622592
#define WS_CANDC  622592                     // NCLS*4 candidate counters
#define WS_ACCUM  622720                     // [0]=sum_loss f32, [1]=cnt_mask u32, [2]=cnt_solid u32
#define WS_DONE   622784                     // [0]=reduce ticket
#define WS_SEL    622848                     // NCLS * {int bin, int rank}
#define WS_NEWTH  623360                     // NCLS*4
#define WS_CONF   623616                     // TPIX*4
#define WS_LOSS   4817920                    // TPIX*4
#define WS_LABEL  9012224                    // TPIX*1
#define WS_CAND   10060800                   // NCLS*CAND_MAX*4 -> end 10372096

// ---------------- K1: register-path staging (unchanged R7; empirical floor 62us) ----------------
#define CH_STRIDE4 (HW/4)                    // channel stride in float4 units
__global__ __launch_bounds__(256, 4)
void k1_pixel(const float* __restrict__ lb_t, const float* __restrict__ la_t,
              float* __restrict__ conf_o, float* __restrict__ loss_o,
              unsigned char* __restrict__ label_o,
              unsigned int* __restrict__ cand_cnt,
              unsigned int* __restrict__ accum_u,
              unsigned int* __restrict__ done)
{
    const int tid = threadIdx.x;
    if (blockIdx.x == 0) {                   // zero control words
        if (tid < NCLS)             cand_cnt[tid] = 0u;
        else if (tid < NCLS + 3)    accum_u[tid - NCLS] = 0u;
        else if (tid < NCLS + 5)    done[tid - NCLS - 3] = 0u;
    }
    const int g    = blockIdx.x * 256 + tid; // float4 index
    const int pix0 = g << 2;
    const int n    = pix0 >> 19;
    const int rem  = pix0 & (HW - 1);
    const float4* bb = (const float4*)(lb_t + (size_t)n * CHW + rem);
    const float4* ab = (const float4*)(la_t + (size_t)n * CHW + rem);

    float mb[4], zb[4], dot[4], ma[4], za[4], a_lab[4];
    int lab[4];
#pragma unroll
    for (int j = 0; j < 4; ++j) {
        mb[j] = -INFINITY; ma[j] = -INFINITY;
        zb[j] = 0.0f; za[j] = 0.0f; dot[j] = 0.0f; a_lab[j] = 0.0f; lab[j] = -1;
    }

    float4 bA0, bA1, bA2, bA3, aA0, aA1, aA2, aA3;     // buffer A
    float4 bB0, bB1, bB2, bB3, aB0, aB1, aB2, aB3;     // buffer B

#define LOADA(c0, NC)                                                          \
    do {                                                                       \
        bA0 = bb[(size_t)(c0 + 0) * CH_STRIDE4];                               \
        aA0 = ab[(size_t)(c0 + 0) * CH_STRIDE4];                               \
        if (NC > 1) { bA1 = bb[(size_t)(c0 + 1) * CH_STRIDE4];                 \
                      aA1 = ab[(size_t)(c0 + 1) * CH_STRIDE4]; }               \
        if (NC > 2) { bA2 = bb[(size_t)(c0 + 2) * CH_STRIDE4];                 \
                      aA2 = ab[(size_t)(c0 + 2) * CH_STRIDE4]; }               \
        if (NC > 3) { bA3 = bb[(size_t)(c0 + 3) * CH_STRIDE4];                 \
                      aA3 = ab[(size_t)(c0 + 3) * CH_STRIDE4]; }               \
        __builtin_amdgcn_sched_barrier(0);                                     \
    } while (0)
#define LOADB(c0, NC)                                                          \
    do {                                                                       \
        bB0 = bb[(size_t)(c0 + 0) * CH_STRIDE4];                               \
        aB0 = ab[(size_t)(c0 + 0) * CH_STRIDE4];                               \
        if (NC > 1) { bB1 = bb[(size_t)(c0 + 1) * CH_STRIDE4];                 \
                      aB1 = ab[(size_t)(c0 + 1) * CH_STRIDE4]; }               \
        if (NC > 2) { bB2 = bb[(size_t)(c0 + 2) * CH_STRIDE4];                 \
                      aB2 = ab[(size_t)(c0 + 2) * CH_STRIDE4]; }               \
        if (NC > 3) { bB3 = bb[(size_t)(c0 + 3) * CH_STRIDE4];                 \
                      aB3 = ab[(size_t)(c0 + 3) * CH_STRIDE4]; }               \
        __builtin_amdgcn_sched_barrier(0);                                     \
    } while (0)
#define STEP(c, bv, av)                                                        \
    do {                                                                       \
        _Pragma("unroll")                                                      \
        for (int j = 0; j < 4; ++j) {                                          \
            float b = ((const float*)&(bv))[j];                                \
            float a = ((const float*)&(av))[j];                                \
            float mn = fmaxf(mb[j], b);                                        \
            float eo = __expf(mb[j] - mn);     /* exp(-inf)=0 handles init */  \
            float en = __expf(b - mn);                                         \
            zb[j]  = zb[j] * eo + en;                                          \
            dot[j] = dot[j] * eo + en * a;                                     \
            bool upd = b > mb[j];              /* first-max-wins (strict >) */ \
            lab[j]   = upd ? (c) : lab[j];                                     \
            a_lab[j] = upd ? a : a_lab[j];                                     \
            mb[j] = mn;                                                        \
            float mna = fmaxf(ma[j], a);                                       \
            za[j] = za[j] * __expf(ma[j] - mna) + __expf(a - mna);             \
            ma[j] = mna;                                                       \
        }                                                                      \
    } while (0)

    LOADA(0, 4);
    LOADB(4, 4);
    STEP(0, bA0, aA0); STEP(1, bA1, aA1); STEP(2, bA2, aA2); STEP(3, bA3, aA3);
    LOADA(8, 4);
    STEP(4, bB0, aB0); STEP(5, bB1, aB1); STEP(6, bB2, aB2); STEP(7, bB3, aB3);
    LOADB(12, 4);
    STEP(8, bA0, aA0); STEP(9, bA1, aA1); STEP(10, bA2, aA2); STEP(11, bA3, aA3);
    LOADA(16, 3);
    STEP(12, bB0, aB0); STEP(13, bB1, aB1); STEP(14, bB2, aB2); STEP(15, bB3, aB3);
    STEP(16, bA0, aA0); STEP(17, bA1, aA1); STEP(18, bA2, aA2);

    float4 cf4, ls4; uchar4 lb4;
#pragma unroll
    for (int j = 0; j < 4; ++j) {
        float cf = 1.0f / zb[j];
        float pa_lab = __expf(a_lab[j] - ma[j]) / za[j];
        float ls = (1.0f - pa_lab) * (ma[j] + __logf(za[j]) - dot[j] / zb[j]);
        ((float*)&cf4)[j] = cf;
        ((float*)&ls4)[j] = ls;
        ((unsigned char*)&lb4)[j] = (unsigned char)lab[j];
    }
    ((float4*)conf_o)[g] = cf4;
    ((float4*)loss_o)[g] = ls4;
    ((uchar4*)label_o)[g] = lb4;
#undef LOADA
#undef LOADB
#undef STEP
}

// ---------------- K2h: partial histograms, 1024 threads for latency hiding ----------------
// R9: R8's fused-run arithmetic showed 32-block hist at 8 waves is latency-bound
// (~1K loads in flight -> ~65GB/s -> 50-80us for 5MB). 16 waves + unroll-4
// independent iterations quadruples MLP.
__global__ __launch_bounds__(1024)
void k2_hist(const float4* __restrict__ conf, const uchar4* __restrict__ label,
             unsigned short* __restrict__ part)
{
    __shared__ unsigned int lh[NCLS * NB];             // 38912 B
    const int t = threadIdx.x;
    for (int w = t; w < NCLS * NB; w += 1024) lh[w] = 0u;
    __syncthreads();

    const int per4  = TPIX / 4 / NPART;                // 8192 float4 per block
    const int base4 = blockIdx.x * per4;
#pragma unroll 4
    for (int i = 0; i < per4 / 1024; ++i) {            // 8 iterations, unrolled 4
        int g = base4 + i * 1024 + t;
        float4 c4 = conf[g];
        uchar4 l4 = label[g];
        float cf[4] = {c4.x, c4.y, c4.z, c4.w};
        int   lb[4] = {l4.x, l4.y, l4.z, l4.w};
#pragma unroll
        for (int k = 0; k < 4; ++k) {
            int bin = (int)(cf[k] * (float)NB);
            bin = bin < (NB - 1) ? bin : (NB - 1);
            atomicAdd(&lh[lb[k] * NB + bin], 1u);      // LDS atomic only
        }
    }
    __syncthreads();

    unsigned short* dst = part + blockIdx.x * (NCLS * NB);
    for (int w = t; w < NCLS * NB; w += 1024) dst[w] = (unsigned short)lh[w];
}

// ---------------- K2s: reduce partials + per-class rank, 512 threads, 1 bin each ----------------
__global__ __launch_bounds__(512)
void k2_select(const unsigned short* __restrict__ part, const float* __restrict__ cls_thresh,
               int* __restrict__ sel, unsigned int* __restrict__ cand_cnt,
               float* __restrict__ cand)
{
    int c = blockIdx.x;
    int t = threadIdx.x;
    float thr = cls_thresh[c];
    int thr_bin = (int)(thr * (float)NB); thr_bin = thr_bin < (NB-1) ? thr_bin : (NB-1);

    int bt = NB - 1 - t;                               // thread t owns bin bt (descending)
    unsigned h = 0;
#pragma unroll 8
    for (int b = 0; b < NPART; ++b)
        h += part[b * (NCLS * NB) + c * NB + bt];
    if (bt == thr_bin) h += 1u;                        // extended multiset: append thr

    __shared__ unsigned sc[512];
    sc[t] = h;
    __syncthreads();
    for (int off = 1; off < 512; off <<= 1) {
        unsigned vt = sc[t];
        unsigned vp = (t >= off) ? sc[t - off] : 0u;
        __syncthreads();
        sc[t] = vt + vp;
        __syncthreads();
    }
    unsigned total_ext = sc[511];                      // count_c + 1
    unsigned cnt = total_ext - 1u;
    int idx = (int)floorf((float)(cnt + 1u) * 0.2f * powf(thr, 8.0f));

    unsigned above = sc[t] - h;                        // strictly above this bin
    if ((unsigned)idx >= above && (unsigned)idx < above + h) {
        sel[2 * c]     = bt;
        sel[2 * c + 1] = (int)((unsigned)idx - above);
        if (bt == thr_bin) {                           // appended thr is a candidate
            unsigned pos = atomicAdd(&cand_cnt[c], 1u);
            if (pos < CAND_MAX) cand[c * CAND_MAX + pos] = thr;
        }
    }
}

// ---------------- K3: gather candidates in selection bin (4 px/thread) ----------------
__global__ __launch_bounds__(256)
void k3_gather(const float4* __restrict__ conf, const uchar4* __restrict__ label,
               const int* __restrict__ sel, unsigned int* __restrict__ cand_cnt,
               float* __restrict__ cand)
{
    int g = blockIdx.x * 256 + threadIdx.x;
    float4 c4 = conf[g];
    uchar4 l4 = label[g];
    float cf[4] = {c4.x, c4.y, c4.z, c4.w};
    int   lb[4] = {l4.x, l4.y, l4.z, l4.w};
#pragma unroll
    for (int i = 0; i < 4; ++i) {
        int bin = (int)(cf[i] * (float)NB);
        bin = bin < (NB - 1) ? bin : (NB - 1);
        if (bin == sel[2 * lb[i]]) {
            unsigned pos = atomicAdd(&cand_cnt[lb[i]], 1u);
            if (pos < CAND_MAX) cand[lb[i] * CAND_MAX + pos] = cf[i];
        }
    }
}

// ---------------- K4: refined exact rank among candidates, 512 threads ----------------
// 19 parallel blocks (one class each) — never fuse into a last-block serial
// phase (R2/R5 lesson: single-block latency wall).
__global__ __launch_bounds__(512)
void k4_thresh(const int* __restrict__ sel, const unsigned int* __restrict__ cand_cnt,
               const float* __restrict__ cand, const float* __restrict__ cls_thresh,
               float* __restrict__ newth)
{
    __shared__ unsigned int subh[SUBB];                // 4 KB
    __shared__ float        sbuf[SCAP];                // 1 KB
    __shared__ unsigned int scnt;
    __shared__ int          sS;
    __shared__ unsigned int sR2;
    __shared__ float        sres;

    const int c = blockIdx.x;
    const int t = threadIdx.x;
    unsigned mc = cand_cnt[c];
    int m = (int)(mc < (unsigned)CAND_MAX ? mc : (unsigned)CAND_MAX);
    int B = sel[2 * c];
    int r = sel[2 * c + 1];
    const float* v = cand + c * CAND_MAX;
    const float scale = (float)NB;

    for (int i = t; i < SUBB; i += 512) subh[i] = 0u;
    if (t == 0) { scnt = 0u; sS = 0; sR2 = 0u; sres = 0.0f; }
    __syncthreads();

    for (int i = t; i < m; i += 512) {
        float x = v[i];
        int s = (int)((x * scale - (float)B) * (float)SUBB);
        s = s < 0 ? 0 : (s > SUBB - 1 ? SUBB - 1 : s);
        atomicAdd(&subh[s], 1u);
    }
    __syncthreads();

    if (t < 64) {                                      // wave 0: descending scan of sub-bins
        int lane = t;
        int cb = SUBB - 16 * (lane + 1);
        unsigned hsum = 0;
        for (int i = 0; i < 16; ++i) hsum += subh[cb + i];
        unsigned incl = hsum;
        for (int off = 1; off < 64; off <<= 1) {
            unsigned q = __shfl_up(incl, off, 64);
            if (lane >= off) incl += q;
        }
        unsigned above = incl - hsum;
        if ((unsigned)r >= above && (unsigned)r < above + hsum) {
            unsigned cum = above;
            for (int i = 15; i >= 0; --i) {
                unsigned h = subh[cb + i];
                if ((unsigned)r < cum + h) { sS = cb + i; sR2 = (unsigned)r - cum; break; }
                cum += h;
            }
        }
    }
    __syncthreads();
    const int S = sS;
    const unsigned r2 = sR2;

    for (int i = t; i < m; i += 512) {                 // gather sub-bin members
        float x = v[i];
        int s = (int)((x * scale - (float)B) * (float)SUBB);
        s = s < 0 ? 0 : (s > SUBB - 1 ? SUBB - 1 : s);
        if (s == S) {
            unsigned p = atomicAdd(&scnt, 1u);
            if (p < (unsigned)SCAP) sbuf[p] = x;
        }
    }
    __syncthreads();
    unsigned cntS = scnt;

    if (cntS <= (unsigned)SCAP) {
        for (int i = t; i < (int)cntS; i += 512) {
            float x = sbuf[i];
            int gc = 0, e = 0;
            for (int j = 0; j < (int)cntS; ++j) {
                float y = sbuf[j];
                gc += (y > x); e += (y == x);
            }
            if (gc <= (int)r2 && (int)r2 < gc + e) sres = x;   // dups write same value
        }
    } else {
        // safety fallback (dead in practice): exact rank restricted to sub-bin S
        for (int i = t; i < m; i += 512) {
            float x = v[i];
            int s = (int)((x * scale - (float)B) * (float)SUBB);
            s = s < 0 ? 0 : (s > SUBB - 1 ? SUBB - 1 : s);
            if (s != S) continue;
            int gc = 0, e = 0;
            for (int j = 0; j < m; ++j) {
                float y = v[j];
                int sj = (int)((y * scale - (float)B) * (float)SUBB);
                sj = sj < 0 ? 0 : (sj > SUBB - 1 ? SUBB - 1 : sj);
                if (sj != S) continue;
                gc += (y > x); e += (y == x);
            }
            if (gc <= (int)r2 && (int)r2 < gc + e) sres = x;
        }
    }
    __syncthreads();
    if (t == 0) {
        float thr = cls_thresh[c];
        float nt = 0.9f * thr + 0.1f * sres;
        if (nt >= 1.0f) nt = 0.999f;
        newth[c] = nt;
    }
}

// ---------------- K5: masked reduction + last-block output (12-byte serial phase) ----------------
__global__ __launch_bounds__(256)
void k5_reduce_out(const float4* __restrict__ conf, const float4* __restrict__ loss,
                   const uchar4* __restrict__ label, const float* __restrict__ newth,
                   float* __restrict__ accum, unsigned int* __restrict__ done,
                   float* __restrict__ out)
{
    __shared__ float th[NCLS];
    if (threadIdx.x < NCLS) th[threadIdx.x] = newth[threadIdx.x];
    __syncthreads();

    int g = blockIdx.x * 256 + threadIdx.x;
    float4 c4 = conf[g];
    float4 s4 = loss[g];
    uchar4 l4 = label[g];
    float cf[4] = {c4.x, c4.y, c4.z, c4.w};
    float lv[4] = {s4.x, s4.y, s4.z, s4.w};
    int   lb[4] = {l4.x, l4.y, l4.z, l4.w};

    float ls = 0.0f; int mask = 0, solid = 0;
#pragma unroll
    for (int i = 0; i < 4; ++i) {
        bool m = cf[i] > th[lb[i]];
        mask  += m ? 1 : 0;
        solid += (cf[i] > 0.8f) ? 1 : 0;
        ls    += m ? fmaxf(lv[i], 1e-8f) : 0.0f;
    }
    for (int off = 32; off > 0; off >>= 1) {
        ls    += __shfl_down(ls, off, 64);
        mask  += __shfl_down(mask, off, 64);
        solid += __shfl_down(solid, off, 64);
    }
    __shared__ float s_ls[4];
    __shared__ int   s_m[4], s_s[4];
    int w = threadIdx.x >> 6;
    if ((threadIdx.x & 63) == 0) { s_ls[w] = ls; s_m[w] = mask; s_s[w] = solid; }
    __syncthreads();
    __shared__ int s_last;
    if (threadIdx.x == 0) {
        float L = s_ls[0] + s_ls[1] + s_ls[2] + s_ls[3];
        int   M = s_m[0] + s_m[1] + s_m[2] + s_m[3];
        int   S = s_s[0] + s_s[1] + s_s[2] + s_s[3];
        atomicAdd(&accum[0], L);
        atomicAdd(&((unsigned int*)accum)[1], (unsigned)M);
        atomicAdd(&((unsigned int*)accum)[2], (unsigned)S);
        __threadfence();                               // release
        s_last = (atomicAdd(&done[0], 1u) == (unsigned)(gridDim.x - 1)) ? 1 : 0;
    }
    __syncthreads();
    if (!s_last) return;
    if (threadIdx.x == 0) {
        __threadfence();                               // acquire (reads 12 bytes only)
        float sum = accum[0];
        unsigned cm = ((const unsigned int*)accum)[1];
        unsigned cs = ((const unsigned int*)accum)[2];
        out[0] = sum / fmaxf((float)cm, 1.0f);
        out[1] = (float)cm / (float)TPIX;
        out[2] = (float)cs / (float)TPIX;
    }
}

extern "C" void kernel_launch(void* const* d_in, const int* in_sizes, int n_in,
                              void* d_out, int out_size, void* d_ws, size_t ws_size,
                              hipStream_t stream)
{
    const float* lb  = (const float*)d_in[0];
    const float* la  = (const float*)d_in[1];
    const float* cth = (const float*)d_in[2];
    float* out = (float*)d_out;

    char* ws = (char*)d_ws;
    unsigned short* part     = (unsigned short*)(ws + WS_PART);
    unsigned int*   cand_cnt = (unsigned int*)(ws + WS_CANDC);
    float*          accum    = (float*)(ws + WS_ACCUM);
    unsigned int*   done     = (unsigned int*)(ws + WS_DONE);
    int*            sel      = (int*)(ws + WS_SEL);
    float*          newth    = (float*)(ws + WS_NEWTH);
    float*          conf     = (float*)(ws + WS_CONF);
    float*          loss     = (float*)(ws + WS_LOSS);
    unsigned char*  label    = (unsigned char*)(ws + WS_LABEL);
    float*          cand     = (float*)(ws + WS_CAND);

    dim3 grd1(TPIX / 4 / 256);           // 1024 blocks, 4 px/thread, register path
    dim3 grd4(TPIX / 4 / 256);           // 1024 blocks, 4 px/thread

    k1_pixel<<<grd1, dim3(256), 0, stream>>>(lb, la, conf, loss, label,
                                             cand_cnt, (unsigned int*)accum, done);
    k2_hist<<<NPART, dim3(1024), 0, stream>>>((const float4*)conf, (const uchar4*)label, part);
    k2_select<<<NCLS, dim3(512), 0, stream>>>(part, cth, sel, cand_cnt, cand);
    k3_gather<<<grd4, dim3(256), 0, stream>>>((const float4*)conf, (const uchar4*)label,
                                              sel, cand_cnt, cand);
    k4_thresh<<<NCLS, dim3(512), 0, stream>>>(sel, cand_cnt, cand, cth, newth);
    k5_reduce_out<<<grd4, dim3(256), 0, stream>>>((const float4*)conf, (const float4*)loss,
                                                  (const uchar4*)label, newth, accum, done, out);
}